// Round 11
// baseline (155.149 us; speedup 1.0000x reference)
//
#include <hip/hip_runtime.h>

#define NUM_BINS 256
#define HW4 65536                  // float4 per plane (512*512/4)
#define NGROUPS 6                  // {img1,img2} x {c0,c1,c2}
#define BPG 512                    // blocks per group
#define GRID (NGROUPS * BPG)       // 3072
#define THREADS 64                 // one wave per block
#define F4_PER_BLOCK 2048          // contiguous 32 KB tile per block
#define ITERS 16                   // 2048 f4 / (2 loads * 64 lanes)

// ---------------------------------------------------------------------------
// Kernel 1: per-lane private u8 sub-histograms, pair-interleaved layout:
//   addr(bin,lane) = (bin>>1)*128 + lane*2 + (bin&1)   -> bank = lane>>1
// (32 banks, 2 lanes/bank on EVERY access, bin-independent; 16 KB = 10
// blocks/CU). Round-7 contiguous streaming (unrolled const-stride loads).
// Batch-8: 8 independent reads, prefix-dup-count, 8 UNCONDITIONAL writes —
// same-lane writes commit in order, so the last duplicate writes the
// correct cumulative total (no divergent guards).
// ---------------------------------------------------------------------------
__global__ __launch_bounds__(THREADS) void hist_kernel(
    const float* __restrict__ img1,
    const float* __restrict__ img2,
    unsigned int* __restrict__ ghist /* [6][256] */) {

    __shared__ unsigned char h8[16384];

    const int lane = threadIdx.x;
    const int lane2 = lane << 1;

    // zero 16384 B: 1024 uint4 / 64 lanes = 16 per lane
    uint4* z = (uint4*)h8;
    #pragma unroll
    for (int i = 0; i < 16; ++i)
        z[i * THREADS + lane] = make_uint4(0u, 0u, 0u, 0u);
    __syncthreads();

    const int gid = blockIdx.x;
    const int group = gid >> 9;                 // 0..5
    const int blk = gid & (BPG - 1);
    const int im = (group >= 3) ? 1 : 0;
    const int c = group - im * 3;
    const int b = blk >> 5;                     // batch plane (32 blocks/plane)
    const int joff = (blk & 31) * F4_PER_BLOCK; // within-plane float4 offset
    const float4* __restrict__ src =
        (const float4*)(im ? img2 : img1) + (size_t)(b * 3 + c) * HW4 + joff + lane;

    // 1-deep software pipeline (round-7 style; unroll exposes more)
    float4 va = src[0];
    float4 vb = src[THREADS];

    #pragma unroll 4
    for (int it = 0; it < ITERS; ++it) {
        float4 na, nb;
        if (it + 1 < ITERS) {
            na = src[(it + 1) * 2 * THREADS];
            nb = src[(it + 1) * 2 * THREADS + THREADS];
        }

        const float xs[8] = {va.x, va.y, va.z, va.w,
                             vb.x, vb.y, vb.z, vb.w};
        int row[8];
        unsigned v0[8];
        int a[8];
        #pragma unroll
        for (int e = 0; e < 8; ++e) {
            const float x = xs[e];
            int bi = (int)(x * 256.0f);            // trunc == floor (x >= 0)
            bi = bi < 0 ? 0 : (bi > 255 ? 255 : bi);
            row[e] = bi;
            // torch.histc: count only x in [0,1]; x==1 -> last bin
            v0[e] = (x >= 0.0f && x <= 1.0f) ? 1u : 0u;
            a[e] = ((bi >> 1) << 7) | lane2 | (bi & 1);
        }

        // 8 independent reads, all in flight before any write
        unsigned v[8];
        #pragma unroll
        for (int e = 0; e < 8; ++e)
            v[e] = h8[a[e]];

        // prefix duplicate count: c[e] = valid(e) + sum_{j<e, same bin} valid(j)
        unsigned cinc[8];
        #pragma unroll
        for (int e = 0; e < 8; ++e) {
            cinc[e] = v0[e];
            #pragma unroll
            for (int j = 0; j < e; ++j)
                cinc[e] += (row[e] == row[j]) ? v0[j] : 0u;
        }

        // unconditional in-order writes: last duplicate writes the full sum
        #pragma unroll
        for (int e = 0; e < 8; ++e)
            h8[a[e]] = (unsigned char)(v[e] + cinc[e]);

        va = na; vb = nb;
    }
    __syncthreads();

    // flush: stripe s (=128 B) holds bins {2s, 2s+1}; rotated word reads
    // -> bank = (w+lane)%32, 2 lanes/bank.
    const unsigned* h32 = (const unsigned*)h8;
    #pragma unroll
    for (int pass = 0; pass < 2; ++pass) {
        const int stripe = (pass << 6) | lane;     // 0..127
        const int wbase = stripe << 5;             // 32 words per stripe
        unsigned s0 = 0, s1 = 0;
        #pragma unroll
        for (int w = 0; w < 32; ++w) {
            const unsigned x = h32[wbase + ((w + lane) & 31)];
            s0 += (x & 0xffu) + ((x >> 16) & 0xffu);        // even bin
            s1 += ((x >> 8) & 0xffu) + (x >> 24);           // odd bin
        }
        if (s0) atomicAdd(&ghist[group * NUM_BINS + (stripe << 1)], s0);
        if (s1) atomicAdd(&ghist[group * NUM_BINS + (stripe << 1) + 1], s1);
    }
}

// ---------------------------------------------------------------------------
// Kernel 2: normalize, cumsum, sum |cdf1 - cdf2|, /3. One block, 256 threads.
// ---------------------------------------------------------------------------
__global__ __launch_bounds__(NUM_BINS) void finalize_kernel(
    const unsigned int* __restrict__ hist, float* __restrict__ out) {

    __shared__ float b1[NUM_BINS];
    __shared__ float b2[NUM_BINS];
    __shared__ float red[NUM_BINS / 64];

    const int t = threadIdx.x;
    float acc = 0.0f;

    for (int c = 0; c < 3; ++c) {
        b1[t] = (float)hist[c * NUM_BINS + t];
        b2[t] = (float)hist[(3 + c) * NUM_BINS + t];
        __syncthreads();
        // Hillis-Steele inclusive scan, 8 steps
        for (int off = 1; off < NUM_BINS; off <<= 1) {
            float a1 = 0.0f, a2 = 0.0f;
            if (t >= off) { a1 = b1[t - off]; a2 = b2[t - off]; }
            __syncthreads();
            b1[t] += a1;
            b2[t] += a2;
            __syncthreads();
        }
        acc += fabsf(b1[t] / b1[NUM_BINS - 1] - b2[t] / b2[NUM_BINS - 1]);
        __syncthreads();                  // protect b1/b2 reuse next channel
    }

    #pragma unroll
    for (int off = 32; off > 0; off >>= 1)
        acc += __shfl_down(acc, off, 64);
    if ((t & 63) == 0) red[t >> 6] = acc;
    __syncthreads();
    if (t == 0)
        out[0] = (red[0] + red[1] + red[2] + red[3]) * (1.0f / 3.0f);
}

// ---------------------------------------------------------------------------
extern "C" void kernel_launch(void* const* d_in, const int* in_sizes, int n_in,
                              void* d_out, int out_size, void* d_ws,
                              size_t ws_size, hipStream_t stream) {
    const float* img1 = (const float*)d_in[0];
    const float* img2 = (const float*)d_in[1];
    float* out = (float*)d_out;
    unsigned int* hist = (unsigned int*)d_ws;   // [6][256] uint32

    // d_ws is poisoned to 0xAA before every launch -> zero hist every call
    hipMemsetAsync(hist, 0, NGROUPS * NUM_BINS * sizeof(unsigned int), stream);

    hist_kernel<<<GRID, THREADS, 0, stream>>>(img1, img2, hist);
    finalize_kernel<<<1, NUM_BINS, 0, stream>>>(hist, out);
}